// Round 2
// baseline (45.771 us; speedup 1.0000x reference)
//
#include <hip/hip_runtime.h>
#include <math.h>

namespace {
typedef float v2f __attribute__((ext_vector_type(2)));

constexpr int B   = 16;
constexpr int CH  = 4;
constexpr int H   = 512;
constexpr int W   = 512;
constexpr int HID = 8;
constexpr int PX  = 8;   // pixels per thread (4 v2f pairs)

static __device__ __forceinline__ v2f splat(float f) { v2f r; r.x = f; r.y = f; return r; }

// One thread computes 8 consecutive output pixels (all 4 channels) at (b, h, w0..w0+7).
// A 64-lane wave covers exactly one full image row.
__global__ __launch_bounds__(256) void ca_kernel(
    const float* __restrict__ x,      // [16,4,512,512]
    const float* __restrict__ w1w,    // [8,16]
    const float* __restrict__ w1b,    // [8]
    const float* __restrict__ w2w,    // [4,8]
    const float* __restrict__ noise,  // [16,1,512,512]
    float* __restrict__ out)          // [16,4,512,512]
{
    const int idx = blockIdx.x * 256 + threadIdx.x;
    const int wg = idx & (W / PX - 1);       // 0..63 (group of 8 columns)
    const int h  = (idx >> 6) & (H - 1);     // 0..511
    const int b  = idx >> 15;                // 0..15

    const int w0 = wg << 3;
    const int wl = (w0 - 1) & (W - 1);       // wrapped left column
    const int wr = (w0 + PX) & (W - 1);      // wrapped right column
    const int hm = (h - 1) & (H - 1);        // wrapped row above
    const int hp = (h + 1) & (H - 1);        // wrapped row below

    // hidden pre-activations: v2f per (hidden unit, pixel-pair)
    v2f hpre[HID][4];
#pragma unroll
    for (int o = 0; o < HID; ++o) {
        const v2f bo = splat(w1b[o]);        // uniform scalar load
#pragma unroll
        for (int p = 0; p < 4; ++p) hpre[o][p] = bo;
    }

    v2f xc[CH][4];                           // center pixels (for residual)

#pragma unroll
    for (int c = 0; c < CH; ++c) {
        const float* base = x + (size_t)(b * CH + c) * (H * W);
        const float* rt = base + hm * W;
        const float* rc = base + h  * W;
        const float* rb = base + hp * W;

        // 10-column windows: [w0-1, w0..w0+7, w0+8] (circular)
        float t[10], m[10], bt[10];
        {
            const float4 a = *(const float4*)(rt + w0);
            const float4 q = *(const float4*)(rt + w0 + 4);
            t[0] = rt[wl]; t[1] = a.x; t[2] = a.y; t[3] = a.z; t[4] = a.w;
            t[5] = q.x; t[6] = q.y; t[7] = q.z; t[8] = q.w; t[9] = rt[wr];
        }
        {
            const float4 a = *(const float4*)(rc + w0);
            const float4 q = *(const float4*)(rc + w0 + 4);
            m[0] = rc[wl]; m[1] = a.x; m[2] = a.y; m[3] = a.z; m[4] = a.w;
            m[5] = q.x; m[6] = q.y; m[7] = q.z; m[8] = q.w; m[9] = rc[wr];
        }
        {
            const float4 a = *(const float4*)(rb + w0);
            const float4 q = *(const float4*)(rb + w0 + 4);
            bt[0] = rb[wl]; bt[1] = a.x; bt[2] = a.y; bt[3] = a.z; bt[4] = a.w;
            bt[5] = q.x; bt[6] = q.y; bt[7] = q.z; bt[8] = q.w; bt[9] = rb[wr];
        }

        // separable column sums: vertical [1,2,1] and [-1,0,1]
        float s[10], d[10];
#pragma unroll
        for (int k = 0; k < 10; ++k) {
            s[k] = fmaf(2.f, m[k], t[k] + bt[k]);
            d[k] = bt[k] - t[k];
        }

#pragma unroll
        for (int p = 0; p < 4; ++p) {
            const int j0 = 2 * p, j1 = 2 * p + 1;
            v2f id, sx, sy, lp;
            // ident = center
            id.x = m[j0 + 1];                      id.y = m[j1 + 1];
            // sobel_x = [1,2,1]_v (x) [-1,0,1]_h
            sx.x = s[j0 + 2] - s[j0];              sx.y = s[j1 + 2] - s[j1];
            // sobel_y = [-1,0,1]_v (x) [1,2,1]_h
            sy.x = fmaf(2.f, d[j0 + 1], d[j0] + d[j0 + 2]);
            sy.y = fmaf(2.f, d[j1 + 1], d[j1] + d[j1 + 2]);
            // lap = [1,2,1](x)[1,2,1] - 16*center
            lp.x = fmaf(-16.f, m[j0 + 1], fmaf(2.f, s[j0 + 1], s[j0] + s[j0 + 2]));
            lp.y = fmaf(-16.f, m[j1 + 1], fmaf(2.f, s[j1 + 1], s[j1] + s[j1 + 2]));

            xc[c][p] = id;

            // accumulate into all hidden units (packed fp32 fma);
            // w1 offsets are compile-time constants -> scalar (K$) loads
#pragma unroll
            for (int o = 0; o < HID; ++o) {
                const float* w1r = w1w + o * 16 + c * 4;
                v2f acc = hpre[o][p];
                acc = __builtin_elementwise_fma(id, splat(w1r[0]), acc);
                acc = __builtin_elementwise_fma(sx, splat(w1r[1]), acc);
                acc = __builtin_elementwise_fma(sy, splat(w1r[2]), acc);
                acc = __builtin_elementwise_fma(lp, splat(w1r[3]), acc);
                hpre[o][p] = acc;
            }
        }
    }

    // stochastic update mask: floor(U + 0.5), exact np semantics
    const float* nrow = noise + ((size_t)b * H + h) * W + w0;
    const float4 n0 = *(const float4*)(nrow);
    const float4 n1 = *(const float4*)(nrow + 4);
    v2f msk[4];
    msk[0].x = floorf(n0.x + 0.5f); msk[0].y = floorf(n0.y + 0.5f);
    msk[1].x = floorf(n0.z + 0.5f); msk[1].y = floorf(n0.w + 0.5f);
    msk[2].x = floorf(n1.x + 0.5f); msk[2].y = floorf(n1.y + 0.5f);
    msk[3].x = floorf(n1.z + 0.5f); msk[3].y = floorf(n1.w + 0.5f);

    // relu
#pragma unroll
    for (int o = 0; o < HID; ++o)
#pragma unroll
        for (int p = 0; p < 4; ++p)
            hpre[o][p] = __builtin_elementwise_max(hpre[o][p], splat(0.f));

    // layer 2 + residual + masked update
#pragma unroll
    for (int c = 0; c < CH; ++c) {
        v2f dd[4] = { splat(0.f), splat(0.f), splat(0.f), splat(0.f) };
#pragma unroll
        for (int o = 0; o < HID; ++o) {
            const v2f wv = splat(w2w[c * HID + o]);   // uniform scalar load
#pragma unroll
            for (int p = 0; p < 4; ++p)
                dd[p] = __builtin_elementwise_fma(hpre[o][p], wv, dd[p]);
        }
        v2f ov[4];
#pragma unroll
        for (int p = 0; p < 4; ++p)
            ov[p] = __builtin_elementwise_fma(dd[p], msk[p], xc[c][p]);

        float* orow = out + ((size_t)(b * CH + c) * H + h) * W + w0;
        float4 o0, o1;
        o0.x = ov[0].x; o0.y = ov[0].y; o0.z = ov[1].x; o0.w = ov[1].y;
        o1.x = ov[2].x; o1.y = ov[2].y; o1.z = ov[3].x; o1.w = ov[3].y;
        *(float4*)(orow)     = o0;
        *(float4*)(orow + 4) = o1;
    }
}
} // namespace

extern "C" void kernel_launch(void* const* d_in, const int* in_sizes, int n_in,
                              void* d_out, int out_size, void* d_ws, size_t ws_size,
                              hipStream_t stream) {
    const float* x     = (const float*)d_in[0];
    const float* w1w   = (const float*)d_in[1];
    const float* w1b   = (const float*)d_in[2];
    const float* w2w   = (const float*)d_in[3];
    const float* noise = (const float*)d_in[4];
    float* out = (float*)d_out;

    const int total_threads = B * H * (W / PX);   // 524,288
    ca_kernel<<<total_threads / 256, 256, 0, stream>>>(x, w1w, w1b, w2w, noise, out);
}

// Round 3
// 35.771 us; speedup vs baseline: 1.2796x; 1.2796x over previous
//
#include <hip/hip_runtime.h>
#include <math.h>

namespace {
typedef float v2f __attribute__((ext_vector_type(2)));

constexpr int B   = 16;
constexpr int CH  = 4;
constexpr int H   = 512;
constexpr int W   = 512;
constexpr int HID = 8;
constexpr int PX  = 8;   // pixels per thread; one 64-lane wave = one full row

static __device__ __forceinline__ v2f splat(float f) { v2f r; r.x = f; r.y = f; return r; }

__global__ __launch_bounds__(256) void ca_kernel(
    const float* __restrict__ x,      // [16,4,512,512]
    const float* __restrict__ w1w,    // [8,16]
    const float* __restrict__ w1b,    // [8]
    const float* __restrict__ w2w,    // [4,8]
    const float* __restrict__ noise,  // [16,1,512,512]
    float* __restrict__ out)          // [16,4,512,512]
{
    const int idx = blockIdx.x * 256 + threadIdx.x;
    const int lane = threadIdx.x & 63;
    const int wg = idx & (W / PX - 1);       // 0..63 == lane (wave covers the row)
    const int h  = (idx >> 6) & (H - 1);     // 0..511
    const int b  = idx >> 15;                // 0..15

    const int w0 = wg << 3;
    const int hm = (h - 1) & (H - 1);        // wrapped row above
    const int hp = (h + 1) & (H - 1);        // wrapped row below
    const int lprev = (lane - 1) & 63;       // W-wrap lives inside the wave
    const int lnext = (lane + 1) & 63;

    // hidden pre-activations: v2f per (hidden unit, pixel-pair)
    v2f hpre[HID][4];
#pragma unroll
    for (int o = 0; o < HID; ++o) {
        const v2f bo = splat(w1b[o]);        // uniform scalar load
#pragma unroll
        for (int p = 0; p < 4; ++p) hpre[o][p] = bo;
    }

    v2f xc[CH][4];                           // center pixels (for residual)

#pragma unroll
    for (int c = 0; c < CH; ++c) {
        const float* base = x + (size_t)(b * CH + c) * (H * W);
        const float* rt = base + hm * W + w0;
        const float* rc = base + h  * W + w0;
        const float* rb = base + hp * W + w0;

        // own 8 columns, aligned float4 loads only
        const float4 t0 = *(const float4*)(rt);
        const float4 t1 = *(const float4*)(rt + 4);
        const float4 c0 = *(const float4*)(rc);
        const float4 c1 = *(const float4*)(rc + 4);
        const float4 b0 = *(const float4*)(rb);
        const float4 b1 = *(const float4*)(rb + 4);

        const float tt[8] = { t0.x, t0.y, t0.z, t0.w, t1.x, t1.y, t1.z, t1.w };
        const float mm[8] = { c0.x, c0.y, c0.z, c0.w, c1.x, c1.y, c1.z, c1.w };
        const float bb[8] = { b0.x, b0.y, b0.z, b0.w, b1.x, b1.y, b1.z, b1.w };

        // vertical column sums: [1,2,1] and [-1,0,1]
        float s[8], d[8];
#pragma unroll
        for (int k = 0; k < 8; ++k) {
            s[k] = fmaf(2.f, mm[k], tt[k] + bb[k]);
            d[k] = bb[k] - tt[k];
        }

        // halo columns via wave-circular shuffle (no gather loads)
        const float sl = __shfl(s[7], lprev, 64);
        const float sr = __shfl(s[0], lnext, 64);
        const float dl = __shfl(d[7], lprev, 64);
        const float dr = __shfl(d[0], lnext, 64);

        const float se[10] = { sl, s[0], s[1], s[2], s[3], s[4], s[5], s[6], s[7], sr };
        const float de[10] = { dl, d[0], d[1], d[2], d[3], d[4], d[5], d[6], d[7], dr };

#pragma unroll
        for (int p = 0; p < 4; ++p) {
            const int j0 = 2 * p, j1 = 2 * p + 1;
            v2f id, sx, sy, lp;
            // ident = center
            id.x = mm[j0]; id.y = mm[j1];
            // sobel_x = [1,2,1]_v (x) [-1,0,1]_h
            sx.x = se[j0 + 2] - se[j0];            sx.y = se[j1 + 2] - se[j1];
            // sobel_y = [-1,0,1]_v (x) [1,2,1]_h
            sy.x = fmaf(2.f, de[j0 + 1], de[j0] + de[j0 + 2]);
            sy.y = fmaf(2.f, de[j1 + 1], de[j1] + de[j1 + 2]);
            // lap = [1,2,1](x)[1,2,1] - 16*center
            lp.x = fmaf(-16.f, mm[j0], fmaf(2.f, se[j0 + 1], se[j0] + se[j0 + 2]));
            lp.y = fmaf(-16.f, mm[j1], fmaf(2.f, se[j1 + 1], se[j1] + se[j1 + 2]));

            xc[c][p] = id;

            // accumulate into all hidden units (packed fp32 fma);
            // w1 offsets compile-time constant -> scalar (K$) loads
#pragma unroll
            for (int o = 0; o < HID; ++o) {
                const float* w1r = w1w + o * 16 + c * 4;
                v2f acc = hpre[o][p];
                acc = __builtin_elementwise_fma(id, splat(w1r[0]), acc);
                acc = __builtin_elementwise_fma(sx, splat(w1r[1]), acc);
                acc = __builtin_elementwise_fma(sy, splat(w1r[2]), acc);
                acc = __builtin_elementwise_fma(lp, splat(w1r[3]), acc);
                hpre[o][p] = acc;
            }
        }
    }

    // stochastic update mask: floor(U + 0.5), exact np semantics
    const float* nrow = noise + ((size_t)b * H + h) * W + w0;
    const float4 n0 = *(const float4*)(nrow);
    const float4 n1 = *(const float4*)(nrow + 4);
    v2f msk[4];
    msk[0].x = floorf(n0.x + 0.5f); msk[0].y = floorf(n0.y + 0.5f);
    msk[1].x = floorf(n0.z + 0.5f); msk[1].y = floorf(n0.w + 0.5f);
    msk[2].x = floorf(n1.x + 0.5f); msk[2].y = floorf(n1.y + 0.5f);
    msk[3].x = floorf(n1.z + 0.5f); msk[3].y = floorf(n1.w + 0.5f);

    // relu
#pragma unroll
    for (int o = 0; o < HID; ++o)
#pragma unroll
        for (int p = 0; p < 4; ++p)
            hpre[o][p] = __builtin_elementwise_max(hpre[o][p], splat(0.f));

    // layer 2 + residual + masked update
#pragma unroll
    for (int c = 0; c < CH; ++c) {
        v2f dd[4] = { splat(0.f), splat(0.f), splat(0.f), splat(0.f) };
#pragma unroll
        for (int o = 0; o < HID; ++o) {
            const v2f wv = splat(w2w[c * HID + o]);   // uniform scalar load
#pragma unroll
            for (int p = 0; p < 4; ++p)
                dd[p] = __builtin_elementwise_fma(hpre[o][p], wv, dd[p]);
        }
        v2f ov[4];
#pragma unroll
        for (int p = 0; p < 4; ++p)
            ov[p] = __builtin_elementwise_fma(dd[p], msk[p], xc[c][p]);

        float* orow = out + ((size_t)(b * CH + c) * H + h) * W + w0;
        float4 o0, o1;
        o0.x = ov[0].x; o0.y = ov[0].y; o0.z = ov[1].x; o0.w = ov[1].y;
        o1.x = ov[2].x; o1.y = ov[2].y; o1.z = ov[3].x; o1.w = ov[3].y;
        *(float4*)(orow)     = o0;
        *(float4*)(orow + 4) = o1;
    }
}
} // namespace

extern "C" void kernel_launch(void* const* d_in, const int* in_sizes, int n_in,
                              void* d_out, int out_size, void* d_ws, size_t ws_size,
                              hipStream_t stream) {
    const float* x     = (const float*)d_in[0];
    const float* w1w   = (const float*)d_in[1];
    const float* w1b   = (const float*)d_in[2];
    const float* w2w   = (const float*)d_in[3];
    const float* noise = (const float*)d_in[4];
    float* out = (float*)d_out;

    const int total_threads = B * H * (W / PX);   // 524,288
    ca_kernel<<<total_threads / 256, 256, 0, stream>>>(x, w1w, w1b, w2w, noise, out);
}